// Round 7
// baseline (104.107 us; speedup 1.0000x reference)
//
#include <hip/hip_runtime.h>
#include <math.h>
#include <stdint.h>

#define RB 256      // block size (all kernels)
#define ROWS 4      // rows per block in row_kernel -> grid 2048 = 8 blocks/CU
#define JT 512      // j-tile (keys) per block in rank_kernel

// float -> orderable uint32 (ascending), packed with index for stable unique keys
__device__ __forceinline__ uint64_t order_key(float f, int idx) {
  uint32_t u = __float_as_uint(f);
  u = (u & 0x80000000u) ? ~u : (u | 0x80000000u);
  return ((uint64_t)u << 32) | (uint32_t)idx;
}

// e_i = log(dur_i + 1e-32) - theta_i ; build sort keys; zero rank; zero out
__global__ void prep_kernel(const float* __restrict__ theta,
                            const float* __restrict__ dur,
                            float* __restrict__ e, uint64_t* __restrict__ key,
                            int* __restrict__ rank, float* __restrict__ out,
                            int n) {
  int i = blockIdx.x * blockDim.x + threadIdx.x;
  if (i < n) {
    float ei = logf(dur[i] + 1e-32f) - theta[i];
    e[i] = ei;
    key[i] = order_key(ei, i);
    rank[i] = 0;
  }
  if (i == 0) out[0] = 0.0f;
}

// rank[i] += #{j in tile : key[j] < key[i]} — LDS-tiled counting-rank.
// All lanes read the same LDS address per jj -> broadcast, conflict-free.
__global__ __launch_bounds__(RB) void rank_kernel(
    const uint64_t* __restrict__ key, int* __restrict__ rank, int n) {
  __shared__ uint64_t kt[JT];
  int i = blockIdx.x * RB + threadIdx.x;
  uint64_t ki = key[i];
  int jbase = blockIdx.y * JT;
  for (int t = threadIdx.x; t < JT; t += RB) kt[t] = key[jbase + t];
  __syncthreads();
  int cnt = 0;
  #pragma unroll 8
  for (int jj = 0; jj < JT; ++jj) {
    cnt += (kt[jj] < ki) ? 1 : 0;
  }
  atomicAdd(&rank[i], cnt);
}

// rank[k] == inv[k] (sorted position of element k). Build:
//   pe[rank[k]].x = SCALE * e[k]    (prescaled e_sorted scatter)
//   pe[k].y      = ev[rank[k]]      (reference's inverse-perm side reorder)
//   th_s[k]      = theta[rank[k]]
__global__ void scatter_kernel(const float* __restrict__ e,
                               const int* __restrict__ rank,
                               const int* __restrict__ ev,
                               const float* __restrict__ theta,
                               float2* __restrict__ pe,
                               float* __restrict__ th_s, int n) {
  const float SCALE = 0.84932180028801904f;  // 1/sqrt(2 ln2)
  int k = blockIdx.x * blockDim.x + threadIdx.x;
  if (k < n) {
    int r = rank[k];
    ((float*)&pe[r])[0] = SCALE * e[k];  // .x — scatter (distinct dword, no race)
    ((float*)&pe[k])[1] = (float)ev[r];  // .y — gather
    th_s[k] = theta[r];
  }
}

// ---------------------------------------------------------------------------
// Main O(n^2) kernel: ROWS rows per block, 2 j's per float4 load, 1-deep
// register prefetch. x = e/sqrt(2 ln2) prescaled, so pdf = exp2(-(xi-xj)^2)
// (neg folds into the VOP3 src modifier). cdf via A&S 7.1.25 3-term erf
// (p = 0.47047, |err|<=2.5e-5) which REUSES the same exponential g.
// ---------------------------------------------------------------------------
__global__ __launch_bounds__(RB) void row_kernel(
    const float2* __restrict__ pe, const float* __restrict__ th_s,
    float* __restrict__ out, int n) {
  const int row0 = blockIdx.x * ROWS;

  float xi[ROWS], sumE[ROWS], sc[ROWS];
  #pragma unroll
  for (int r = 0; r < ROWS; ++r) {
    xi[r] = pe[row0 + r].x;     // block-uniform -> scalar load
    sumE[r] = 0.0f;
    sc[r] = 0.0f;
  }

  // t = 1/(1 + 0.47047*|d|/sqrt2) with d = dp*sqrt(2 ln2):
  // P2S = 0.47047 * sqrt(ln2) = 0.39169197
  const float P2S = 0.39169197f;
  const float4* pe4 = (const float4*)pe;
  const int it_count = n / (2 * RB);     // 16 for n=8192
  float4 q = pe4[threadIdx.x];

  for (int it = 0; it < it_count; ++it) {
    float4 qn = pe4[(it + 1) * RB + threadIdx.x];  // prefetch (pad tail unused)
    #pragma unroll
    for (int half = 0; half < 2; ++half) {
      float xj  = half ? q.z : q.x;
      float evj = half ? q.w : q.y;
      #pragma unroll
      for (int r = 0; r < ROWS; ++r) {
        float dp = xi[r] - xj;                          // prescaled diff
        float g = __builtin_amdgcn_exp2f(-(dp * dp));   // exp(-d^2/2)
        sumE[r] = fmaf(g, evj, sumE[r]);
        float tt = __builtin_amdgcn_rcpf(fmaf(P2S, __builtin_fabsf(dp), 1.0f));
        // A&S 7.1.25: coeffs sum to exactly 1 -> erf(0) = 0 exact
        float poly = tt * (0.3480242f + tt * (-0.0958798f + tt * 0.7478556f));
        float erfa = fmaf(-poly, g, 1.0f);
        sc[r] += __builtin_copysignf(erfa, dp);         // sum sign*erf; +0.5n later
      }
    }
    q = qn;
  }

  // per-wave shuffle reduction
  #pragma unroll
  for (int r = 0; r < ROWS; ++r) {
    #pragma unroll
    for (int off = 32; off > 0; off >>= 1) {
      sumE[r] += __shfl_down(sumE[r], off, 64);
      sc[r]   += __shfl_down(sc[r], off, 64);
    }
  }

  __shared__ float red[RB / 64][ROWS][2];
  __shared__ float termbuf[ROWS];
  const int wave = threadIdx.x >> 6;
  const int lane = threadIdx.x & 63;
  if (lane == 0) {
    #pragma unroll
    for (int r = 0; r < ROWS; ++r) {
      red[wave][r][0] = sumE[r];
      red[wave][r][1] = sc[r];
    }
  }
  __syncthreads();

  if (threadIdx.x < ROWS) {
    const int r = threadIdx.x;
    float tE = 0.0f, tS = 0.0f;
    #pragma unroll
    for (int w = 0; w < RB / 64; ++w) { tE += red[w][r][0]; tS += red[w][r][1]; }
    const float fn = (float)n;
    float condE = tE * 0.39894228040143267794f / fn + fn * 1e-32f;
    float surv  = (0.5f * fn + 0.5f * tS) / fn;   // sum cdf / n
    const int i = row0 + r;
    termbuf[r] = (__logf(condE) - __logf(surv) + th_s[i]) * pe[i].y;
  }
  __syncthreads();

  if (threadIdx.x == 0) {   // one atomic per block
    float s = 0.0f;
    #pragma unroll
    for (int r = 0; r < ROWS; ++r) s += termbuf[r];
    atomicAdd(out, -s / (float)n);
  }
}

extern "C" void kernel_launch(void* const* d_in, const int* in_sizes, int n_in,
                              void* d_out, int out_size, void* d_ws, size_t ws_size,
                              hipStream_t stream) {
  const float* theta = (const float*)d_in[0];   // log_h (n,1) fp32
  const float* dur   = (const float*)d_in[1];   // durations (n,) fp32
  const int*   ev    = (const int*)d_in[2];     // events (n,) int32
  float* out = (float*)d_out;
  const int n = in_sizes[1];

  // workspace layout (8-byte aligned first); pe padded by 2*RB float2 for the
  // float4 prefetch tail (loaded but never used in arithmetic).
  char* ws = (char*)d_ws;
  uint64_t* key   = (uint64_t*)ws;  ws += n * sizeof(uint64_t);
  float2*   pe    = (float2*)ws;    ws += (n + 2 * RB) * sizeof(float2);
  float*    e     = (float*)ws;     ws += n * sizeof(float);
  int*      rank  = (int*)ws;       ws += n * sizeof(int);
  float*    th_s  = (float*)ws;     ws += n * sizeof(float);

  int nb = (n + RB - 1) / RB;
  prep_kernel<<<nb, RB, 0, stream>>>(theta, dur, e, key, rank, out, n);
  rank_kernel<<<dim3(n / RB, n / JT), RB, 0, stream>>>(key, rank, n);
  scatter_kernel<<<nb, RB, 0, stream>>>(e, rank, ev, theta, pe, th_s, n);
  row_kernel<<<n / ROWS, RB, 0, stream>>>(pe, th_s, out, n);
}

// Round 8
// 103.132 us; speedup vs baseline: 1.0095x; 1.0095x over previous
//
#include <hip/hip_runtime.h>
#include <math.h>
#include <stdint.h>

#define RB 256      // block size (all kernels)
#define ROWS 4      // rows per block in row_kernel -> grid 2048
#define JT 512      // j-tile (keys) per block in rank_kernel

typedef float v2f __attribute__((ext_vector_type(2)));

// float -> orderable uint32 (ascending), packed with index for stable unique keys
__device__ __forceinline__ uint64_t order_key(float f, int idx) {
  uint32_t u = __float_as_uint(f);
  u = (u & 0x80000000u) ? ~u : (u | 0x80000000u);
  return ((uint64_t)u << 32) | (uint32_t)idx;
}

// e_i = log(dur_i + 1e-32) - theta_i ; build sort keys; zero rank; zero out
__global__ void prep_kernel(const float* __restrict__ theta,
                            const float* __restrict__ dur,
                            float* __restrict__ e, uint64_t* __restrict__ key,
                            int* __restrict__ rank, float* __restrict__ out,
                            int n) {
  int i = blockIdx.x * blockDim.x + threadIdx.x;
  if (i < n) {
    float ei = logf(dur[i] + 1e-32f) - theta[i];
    e[i] = ei;
    key[i] = order_key(ei, i);
    rank[i] = 0;
  }
  if (i == 0) out[0] = 0.0f;
}

// rank[i] += #{j in tile : key[j] < key[i]} — LDS-tiled counting-rank.
__global__ __launch_bounds__(RB) void rank_kernel(
    const uint64_t* __restrict__ key, int* __restrict__ rank, int n) {
  __shared__ uint64_t kt[JT];
  int i = blockIdx.x * RB + threadIdx.x;
  uint64_t ki = key[i];
  int jbase = blockIdx.y * JT;
  for (int t = threadIdx.x; t < JT; t += RB) kt[t] = key[jbase + t];
  __syncthreads();
  int cnt = 0;
  #pragma unroll 8
  for (int jj = 0; jj < JT; ++jj) {
    cnt += (kt[jj] < ki) ? 1 : 0;
  }
  atomicAdd(&rank[i], cnt);
}

// rank[k] == inv[k]. SoA outputs:
//   xs[rank[k]] = SCALE * e[k]     (prescaled e_sorted, scatter)
//   evs[k]      = ev[rank[k]]      (reference's inverse-perm side reorder)
//   th_s[k]     = theta[rank[k]]
__global__ void scatter_kernel(const float* __restrict__ e,
                               const int* __restrict__ rank,
                               const int* __restrict__ ev,
                               const float* __restrict__ theta,
                               float* __restrict__ xs,
                               float* __restrict__ evs,
                               float* __restrict__ th_s, int n) {
  const float SCALE = 0.84932180028801904f;  // 1/sqrt(2 ln2)
  int k = blockIdx.x * blockDim.x + threadIdx.x;
  if (k < n) {
    int r = rank[k];
    xs[r] = SCALE * e[k];
    evs[k] = (float)ev[r];
    th_s[k] = theta[r];
  }
}

// ---------------------------------------------------------------------------
// Main O(n^2) kernel — PACKED fp32: 2 j's per iteration as float2 ext-vectors
// so the backend can form v_pk_fma_f32 / v_pk_add_f32 / v_pk_mul_f32
// (full-rate packed fp32, gfx90a+). SoA loads (dwordx2) land each j-pair as
// an adjacent VGPR pair — no repack movs. exp2/rcp stay scalar on the trans
// pipe (2 per packed iteration each).
// x = e/sqrt(2 ln2) prescaled: pdf = exp2(-(xi-xj)^2); cdf via A&S 7.1.25
// 3-term erf (p=0.47047, |err|<=2.5e-5) reusing the same exponential g.
// ---------------------------------------------------------------------------
__global__ __launch_bounds__(RB) void row_kernel(
    const float* __restrict__ xs, const float* __restrict__ evs,
    const float* __restrict__ th_s, float* __restrict__ out, int n) {
  const int row0 = blockIdx.x * ROWS;

  v2f xi[ROWS], sumE[ROWS], sc[ROWS];
  #pragma unroll
  for (int r = 0; r < ROWS; ++r) {
    float x = xs[row0 + r];     // block-uniform -> scalar load
    xi[r] = (v2f){x, x};
    sumE[r] = (v2f){0.0f, 0.0f};
    sc[r] = (v2f){0.0f, 0.0f};
  }

  // t = 1/(1 + 0.47047*|d|/sqrt2), d = dp*sqrt(2 ln2): P2S = 0.47047*sqrt(ln2)
  const v2f P2S = (v2f){0.39169197f, 0.39169197f};
  const v2f ONE = (v2f){1.0f, 1.0f};
  const v2f C1 = (v2f){0.3480242f, 0.3480242f};
  const v2f C2 = (v2f){-0.0958798f, -0.0958798f};
  const v2f C3 = (v2f){0.7478556f, 0.7478556f};

  const v2f* xs2 = (const v2f*)xs;
  const v2f* evs2 = (const v2f*)evs;
  const int it_count = n / (2 * RB);     // 16 for n=8192
  v2f xq = xs2[threadIdx.x];
  v2f eq = evs2[threadIdx.x];

  for (int it = 0; it < it_count; ++it) {
    int pf = (it + 1) * RB + threadIdx.x;   // prefetch (pad tail, never consumed)
    v2f xqn = xs2[pf];
    v2f eqn = evs2[pf];
    #pragma unroll
    for (int r = 0; r < ROWS; ++r) {
      v2f dp = xi[r] - xq;                               // pk_add(neg)
      v2f m = dp * dp;                                   // pk_mul
      v2f g = (v2f){__builtin_amdgcn_exp2f(-m.x),        // trans; neg = src mod
                    __builtin_amdgcn_exp2f(-m.y)};
      sumE[r] = __builtin_elementwise_fma(g, eq, sumE[r]);          // pk_fma
      v2f adp = __builtin_elementwise_abs(dp);
      v2f targ = __builtin_elementwise_fma(P2S, adp, ONE);          // pk_fma
      v2f tt = (v2f){__builtin_amdgcn_rcpf(targ.x),      // trans
                     __builtin_amdgcn_rcpf(targ.y)};
      v2f poly = tt * __builtin_elementwise_fma(
                     tt, __builtin_elementwise_fma(tt, C3, C2), C1); // 2 pk_fma + pk_mul
      v2f erfa = __builtin_elementwise_fma(-poly, g, ONE);           // pk_fma
      v2f s = (v2f){__builtin_copysignf(erfa.x, dp.x),   // bfi x2
                    __builtin_copysignf(erfa.y, dp.y)};
      sc[r] += s;                                        // pk_add
    }
    xq = xqn;
    eq = eqn;
  }

  // horizontal + per-wave shuffle reduction
  float hE[ROWS], hS[ROWS];
  #pragma unroll
  for (int r = 0; r < ROWS; ++r) {
    hE[r] = sumE[r].x + sumE[r].y;
    hS[r] = sc[r].x + sc[r].y;
    #pragma unroll
    for (int off = 32; off > 0; off >>= 1) {
      hE[r] += __shfl_down(hE[r], off, 64);
      hS[r] += __shfl_down(hS[r], off, 64);
    }
  }

  __shared__ float red[RB / 64][ROWS][2];
  __shared__ float termbuf[ROWS];
  const int wave = threadIdx.x >> 6;
  const int lane = threadIdx.x & 63;
  if (lane == 0) {
    #pragma unroll
    for (int r = 0; r < ROWS; ++r) {
      red[wave][r][0] = hE[r];
      red[wave][r][1] = hS[r];
    }
  }
  __syncthreads();

  if (threadIdx.x < ROWS) {
    const int r = threadIdx.x;
    float tE = 0.0f, tS = 0.0f;
    #pragma unroll
    for (int w = 0; w < RB / 64; ++w) { tE += red[w][r][0]; tS += red[w][r][1]; }
    const float fn = (float)n;
    float condE = tE * 0.39894228040143267794f / fn + fn * 1e-32f;
    float surv  = (0.5f * fn + 0.5f * tS) / fn;   // sum cdf / n
    const int i = row0 + r;
    termbuf[r] = (__logf(condE) - __logf(surv) + th_s[i]) * evs[i];
  }
  __syncthreads();

  if (threadIdx.x == 0) {   // one atomic per block
    float s = 0.0f;
    #pragma unroll
    for (int r = 0; r < ROWS; ++r) s += termbuf[r];
    atomicAdd(out, -s / (float)n);
  }
}

extern "C" void kernel_launch(void* const* d_in, const int* in_sizes, int n_in,
                              void* d_out, int out_size, void* d_ws, size_t ws_size,
                              hipStream_t stream) {
  const float* theta = (const float*)d_in[0];   // log_h (n,1) fp32
  const float* dur   = (const float*)d_in[1];   // durations (n,) fp32
  const int*   ev    = (const int*)d_in[2];     // events (n,) int32
  float* out = (float*)d_out;
  const int n = in_sizes[1];

  // workspace (8-byte aligned first); xs/evs padded 2*RB floats for the
  // prefetch tail (loaded but never consumed in arithmetic).
  char* ws = (char*)d_ws;
  uint64_t* key  = (uint64_t*)ws;  ws += n * sizeof(uint64_t);
  float*    xs   = (float*)ws;     ws += (n + 2 * RB) * sizeof(float);
  float*    evs  = (float*)ws;     ws += (n + 2 * RB) * sizeof(float);
  float*    e    = (float*)ws;     ws += n * sizeof(float);
  int*      rank = (int*)ws;       ws += n * sizeof(int);
  float*    th_s = (float*)ws;     ws += n * sizeof(float);

  int nb = (n + RB - 1) / RB;
  prep_kernel<<<nb, RB, 0, stream>>>(theta, dur, e, key, rank, out, n);
  rank_kernel<<<dim3(n / RB, n / JT), RB, 0, stream>>>(key, rank, n);
  scatter_kernel<<<nb, RB, 0, stream>>>(e, rank, ev, theta, xs, evs, th_s, n);
  row_kernel<<<n / ROWS, RB, 0, stream>>>(xs, evs, th_s, out, n);
}

// Round 9
// 88.272 us; speedup vs baseline: 1.1794x; 1.1683x over previous
//
#include <hip/hip_runtime.h>
#include <math.h>
#include <stdint.h>

#define RB 256      // block size
#define JT 512      // j-tile (keys) per block in rank_kernel
#define GM 2048     // Gauss-transform grid points

#define SCALE 0.84932180028801904f   // 1/sqrt(2 ln2): exp(-d^2/2) = exp2(-(SCALE*d)^2)
#define SQRT2PI 2.5066282746310002f

// float -> orderable uint32 (ascending)
__device__ __forceinline__ unsigned float2ord(float f) {
  unsigned u = __float_as_uint(f);
  return (u & 0x80000000u) ? ~u : (u | 0x80000000u);
}
__device__ __forceinline__ float ord2float(unsigned u) {
  return __uint_as_float((u & 0x80000000u) ? (u ^ 0x80000000u) : ~u);
}
__device__ __forceinline__ uint64_t order_key(float f, int idx) {
  return ((uint64_t)float2ord(f) << 32) | (unsigned)idx;
}

// grid geometry from device min/max (identical float ops in every consumer)
__device__ __forceinline__ void grid_geom(const unsigned* mm, float* x0, float* hx) {
  float emin = ord2float(mm[0]), emax = ord2float(mm[1]);
  float a = fmaf(SCALE, emin, -7.0f);        // SCALE*emin - 7  (margin ~8 sigma)
  float b = fmaf(SCALE, emax, 7.0f);
  *x0 = a;
  *hx = (b - a) / (float)(GM - 1);
}

// zero the 4 GT accumulator arrays; init min/max
__global__ void init_kernel(float* gbuf, unsigned* mm) {
  int i = blockIdx.x * blockDim.x + threadIdx.x;
  if (i < 4 * GM) gbuf[i] = 0.0f;
  if (i == 0) { mm[0] = 0xFFFFFFFFu; mm[1] = 0u; }
}

// e_i = log(dur+1e-32)-theta; keys; rank=0; out=0; global min/max of e
__global__ void prep_kernel(const float* __restrict__ theta,
                            const float* __restrict__ dur,
                            float* __restrict__ e, uint64_t* __restrict__ key,
                            int* __restrict__ rank, float* __restrict__ out,
                            unsigned* __restrict__ mm, int n) {
  int i = blockIdx.x * blockDim.x + threadIdx.x;
  unsigned umin = 0xFFFFFFFFu, umax = 0u;
  if (i < n) {
    float ei = logf(dur[i] + 1e-32f) - theta[i];
    e[i] = ei;
    key[i] = order_key(ei, i);
    rank[i] = 0;
    umin = umax = float2ord(ei);
  }
  if (i == 0) out[0] = 0.0f;
  #pragma unroll
  for (int off = 32; off > 0; off >>= 1) {
    umin = min(umin, (unsigned)__shfl_xor((int)umin, off, 64));
    umax = max(umax, (unsigned)__shfl_xor((int)umax, off, 64));
  }
  if ((threadIdx.x & 63) == 0) {
    atomicMin(&mm[0], umin);
    atomicMax(&mm[1], umax);
  }
}

// counting-rank (== inverse permutation), LDS-tiled (proven in R4-R8)
__global__ __launch_bounds__(RB) void rank_kernel(
    const uint64_t* __restrict__ key, int* __restrict__ rank, int n) {
  __shared__ uint64_t kt[JT];
  int i = blockIdx.x * RB + threadIdx.x;
  uint64_t ki = key[i];
  int jbase = blockIdx.y * JT;
  for (int t = threadIdx.x; t < JT; t += RB) kt[t] = key[jbase + t];
  __syncthreads();
  int cnt = 0;
  #pragma unroll 8
  for (int jj = 0; jj < JT; ++jj) cnt += (kt[jj] < ki) ? 1 : 0;
  atomicAdd(&rank[i], cnt);
}

// xs[rank[k]] = SCALE*e[k]; evs[k] = ev[rank[k]]; th_s[k] = theta[rank[k]]
__global__ void scatter_kernel(const float* __restrict__ e,
                               const int* __restrict__ rank,
                               const int* __restrict__ ev,
                               const float* __restrict__ theta,
                               float* __restrict__ xs, float* __restrict__ evs,
                               float* __restrict__ th_s, int n) {
  int k = blockIdx.x * blockDim.x + threadIdx.x;
  if (k < n) {
    int r = rank[k];
    xs[r] = SCALE * e[k];
    evs[k] = (float)ev[r];
    th_s[k] = theta[r];
  }
}

// ---------------------------------------------------------------------------
// Gauss transform on the grid. Thread owns grid point m; sources are
// block-uniform (scalar loads). Accumulates, with dp = x_m - x_j (prescaled):
//   A = sum g            (Ghat, also F' for Hermite)
//   B = sum ev*g         (pdf*ev sum; B' = -2D)
//   C = sum dp*g         (Ghat' = -2C; trapezoid correction)
//   D = sum ev*dp*g
// ---------------------------------------------------------------------------
__global__ __launch_bounds__(RB) void gt_kernel(
    const float* __restrict__ xs, const float* __restrict__ evs,
    const unsigned* __restrict__ mm, float* __restrict__ gbuf, int n) {
  float x0, hx;
  grid_geom(mm, &x0, &hx);
  int m = blockIdx.x * RB + threadIdx.x;        // gridDim.x = GM/RB
  float xm = fmaf((float)m, hx, x0);
  int chunk = n >> 6;                            // gridDim.y = 64
  int jb = blockIdx.y * chunk;
  float a = 0.0f, b = 0.0f, c = 0.0f, d = 0.0f;
  #pragma unroll 8
  for (int jj = 0; jj < chunk; ++jj) {
    float xj = xs[jb + jj];                      // uniform -> s_load
    float ev = evs[jb + jj];
    float dp = xm - xj;
    float g = __builtin_amdgcn_exp2f(-(dp * dp));
    float evg = ev * g;
    a += g;
    b += evg;
    c = fmaf(dp, g, c);
    d = fmaf(dp, evg, d);
  }
  atomicAdd(&gbuf[m], a);
  atomicAdd(&gbuf[GM + m], b);
  atomicAdd(&gbuf[2 * GM + m], c);
  atomicAdd(&gbuf[3 * GM + m], d);
}

// ---------------------------------------------------------------------------
// Prefix integral Fx[m] = int_{x_0}^{x_m} Ghat dx via derivative-corrected
// trapezoid (error O(h^5) per interval):
//   dF_k = hx/2*(A_k+A_{k+1}) + hx^2/6*(C_{k+1}-C_k)
// Single block, Hillis-Steele scan in double.
// ---------------------------------------------------------------------------
__global__ __launch_bounds__(1024) void scan_kernel(
    const float* __restrict__ gbuf, const unsigned* __restrict__ mm,
    float* __restrict__ Fx) {
  __shared__ double sh[1024];
  float x0, hx;
  grid_geom(mm, &x0, &hx);
  const float* A = gbuf;
  const float* C = gbuf + 2 * GM;
  int t = threadIdx.x;
  int k0 = 2 * t, k1 = 2 * t + 1;
  double h = (double)hx, h26 = h * h / 6.0;
  double d0 = 0.5 * h * ((double)A[k0] + (double)A[k0 + 1]) +
              h26 * ((double)C[k0 + 1] - (double)C[k0]);          // k0 <= 2046
  double d1 = (k1 < GM - 1)
                  ? 0.5 * h * ((double)A[k1] + (double)A[k1 + 1]) +
                    h26 * ((double)C[k1 + 1] - (double)C[k1])
                  : 0.0;
  double pair = d0 + d1;
  sh[t] = pair;
  __syncthreads();
  for (int off = 1; off < 1024; off <<= 1) {
    double v = (t >= off) ? sh[t - off] : 0.0;
    __syncthreads();
    sh[t] += v;
    __syncthreads();
  }
  double excl = sh[t] - pair;
  if (t == 0) Fx[0] = 0.0f;
  Fx[k0 + 1] = (float)(excl + d0);
  if (k1 + 1 <= GM - 1) Fx[k1 + 1] = (float)(excl + d0 + d1);
}

// ---------------------------------------------------------------------------
// Per-element cubic Hermite interpolation of F (cdf-sum) and B (pdf*ev sum),
// then the loss terms. One block = 256 elements; one atomic per block.
// ---------------------------------------------------------------------------
__global__ __launch_bounds__(RB) void final_kernel(
    const float* __restrict__ xs, const float* __restrict__ evs,
    const float* __restrict__ th_s, const float* __restrict__ gbuf,
    const float* __restrict__ Fx, const unsigned* __restrict__ mm,
    float* __restrict__ out, int n) {
  float x0, hx;
  grid_geom(mm, &x0, &hx);
  const float* A = gbuf;
  const float* B = gbuf + GM;
  const float* D = gbuf + 3 * GM;
  int i = blockIdx.x * RB + threadIdx.x;

  float term = 0.0f;
  if (i < n) {
    float x = xs[i];
    double u = ((double)x - (double)x0) / (double)hx;
    int m = (int)u;
    m = min(max(m, 0), GM - 2);
    float t = (float)(u - (double)m);
    float t2 = t * t, t3 = t2 * t;
    float h00 = 2.0f * t3 - 3.0f * t2 + 1.0f;
    float h01 = 3.0f * t2 - 2.0f * t3;
    float h10 = t3 - 2.0f * t2 + t;
    float h11 = t3 - t2;
    float Fi = Fx[m] * h00 + Fx[m + 1] * h01 + hx * (A[m] * h10 + A[m + 1] * h11);
    float Bi = B[m] * h00 + B[m + 1] * h01 -
               2.0f * hx * (D[m] * h10 + D[m + 1] * h11);
    const float fn = (float)n;
    float PhiSum = fmaxf(Fi * (1.0f / SCALE / SQRT2PI), 1e-20f);   // >= 0.5 in exact math
    float condE = fmaxf(Bi, 0.0f) * (1.0f / SQRT2PI) / fn + fn * 1e-32f;
    float surv = PhiSum / fn;
    term = (__logf(condE) - __logf(surv) + th_s[i]) * evs[i];
  }

  #pragma unroll
  for (int off = 32; off > 0; off >>= 1) term += __shfl_down(term, off, 64);
  __shared__ float red[RB / 64];
  int wave = threadIdx.x >> 6, lane = threadIdx.x & 63;
  if (lane == 0) red[wave] = term;
  __syncthreads();
  if (threadIdx.x == 0) {
    float s = 0.0f;
    #pragma unroll
    for (int w = 0; w < RB / 64; ++w) s += red[w];
    atomicAdd(out, -s / (float)n);
  }
}

extern "C" void kernel_launch(void* const* d_in, const int* in_sizes, int n_in,
                              void* d_out, int out_size, void* d_ws, size_t ws_size,
                              hipStream_t stream) {
  const float* theta = (const float*)d_in[0];   // log_h (n,1) fp32
  const float* dur   = (const float*)d_in[1];   // durations (n,) fp32
  const int*   ev    = (const int*)d_in[2];     // events (n,) int32
  float* out = (float*)d_out;
  const int n = in_sizes[1];

  // workspace layout (8-byte aligned first)
  char* ws = (char*)d_ws;
  uint64_t* key  = (uint64_t*)ws;  ws += n * sizeof(uint64_t);
  float*    xs   = (float*)ws;     ws += n * sizeof(float);
  float*    evs  = (float*)ws;     ws += n * sizeof(float);
  float*    e    = (float*)ws;     ws += n * sizeof(float);
  int*      rank = (int*)ws;       ws += n * sizeof(int);
  float*    th_s = (float*)ws;     ws += n * sizeof(float);
  float*    gbuf = (float*)ws;     ws += 4 * GM * sizeof(float);  // A|B|C|D
  float*    Fx   = (float*)ws;     ws += GM * sizeof(float);
  unsigned* mm   = (unsigned*)ws;  ws += 2 * sizeof(unsigned);

  int nb = (n + RB - 1) / RB;
  init_kernel<<<(4 * GM + RB - 1) / RB, RB, 0, stream>>>(gbuf, mm);
  prep_kernel<<<nb, RB, 0, stream>>>(theta, dur, e, key, rank, out, mm, n);
  rank_kernel<<<dim3(n / RB, n / JT), RB, 0, stream>>>(key, rank, n);
  scatter_kernel<<<nb, RB, 0, stream>>>(e, rank, ev, theta, xs, evs, th_s, n);
  gt_kernel<<<dim3(GM / RB, 64), RB, 0, stream>>>(xs, evs, mm, gbuf, n);
  scan_kernel<<<1, 1024, 0, stream>>>(gbuf, mm, Fx);
  final_kernel<<<nb, RB, 0, stream>>>(xs, evs, th_s, gbuf, Fx, mm, out, n);
}

// Round 10
// 83.676 us; speedup vs baseline: 1.2442x; 1.0549x over previous
//
#include <hip/hip_runtime.h>
#include <math.h>
#include <stdint.h>

#define RB 256      // block size
#define JT 512      // j-tile (keys) per block in rank_kernel
#define GM 2048     // Gauss-transform grid points
#define YS 64       // source-splits in gt_kernel

#define SCALE 0.84932180028801904f   // 1/sqrt(2 ln2): exp(-d^2/2) = exp2(-(SCALE*d)^2)
#define SQRT2PI 2.5066282746310002f
#define KFP 0.46971863934f           // 1/(SCALE*sqrt(2pi)) : dPhiSum/dx = KFP*A
#define LN2 0.69314718056f

// float -> orderable uint32 (ascending), packed with index for stable unique keys
__device__ __forceinline__ uint64_t order_key(float f, int idx) {
  unsigned u = __float_as_uint(f);
  u = (u & 0x80000000u) ? ~u : (u | 0x80000000u);
  return ((uint64_t)u << 32) | (unsigned)idx;
}

// grid geometry from the sorted endpoints (identical fp ops in every consumer)
__device__ __forceinline__ void grid_geom(const float* xs, int n, float* x0, float* hx) {
  float a = xs[0] - 7.0f;        // ~8 sigma margin in prescaled units
  float b = xs[n - 1] + 7.0f;
  *x0 = a;
  *hx = (b - a) / (float)(GM - 1);
}

// e_i = log(dur+1e-32)-theta; keys; rank=0; out=0; zero gbuf (4*GM == n == 8192)
__global__ void prep_kernel(const float* __restrict__ theta,
                            const float* __restrict__ dur,
                            float* __restrict__ e, uint64_t* __restrict__ key,
                            int* __restrict__ rank, float* __restrict__ out,
                            float* __restrict__ gbuf, int n) {
  int i = blockIdx.x * blockDim.x + threadIdx.x;
  if (i < n) {
    float ei = logf(dur[i] + 1e-32f) - theta[i];
    e[i] = ei;
    key[i] = order_key(ei, i);
    rank[i] = 0;
  }
  if (i < 4 * GM) gbuf[i] = 0.0f;
  if (i == 0) out[0] = 0.0f;
}

// counting-rank (== inverse permutation), LDS-tiled (validated R4-R9)
__global__ __launch_bounds__(RB) void rank_kernel(
    const uint64_t* __restrict__ key, int* __restrict__ rank, int n) {
  __shared__ uint64_t kt[JT];
  int i = blockIdx.x * RB + threadIdx.x;
  uint64_t ki = key[i];
  int jbase = blockIdx.y * JT;
  for (int t = threadIdx.x; t < JT; t += RB) kt[t] = key[jbase + t];
  __syncthreads();
  int cnt = 0;
  #pragma unroll 8
  for (int jj = 0; jj < JT; ++jj) cnt += (kt[jj] < ki) ? 1 : 0;
  atomicAdd(&rank[i], cnt);
}

// xs[rank[k]] = SCALE*e[k]; evs[k] = ev[rank[k]]; th_s[k] = theta[rank[k]]
// (reference's inverse-perm side reorder, validated R2-R9)
__global__ void scatter_kernel(const float* __restrict__ e,
                               const int* __restrict__ rank,
                               const int* __restrict__ ev,
                               const float* __restrict__ theta,
                               float* __restrict__ xs, float* __restrict__ evs,
                               float* __restrict__ th_s, int n) {
  int k = blockIdx.x * blockDim.x + threadIdx.x;
  if (k < n) {
    int r = rank[k];
    xs[r] = SCALE * e[k];
    evs[k] = (float)ev[r];
    th_s[k] = theta[r];
  }
}

// ---------------------------------------------------------------------------
// Gauss transform on the grid. Thread owns grid point m; sources block-uniform
// (scalar loads). dp = x_m - x_j (prescaled). Accumulates:
//   A = sum g                      (pdf-sum basis; FPhi' = KFP*A)
//   B = sum ev*g                   (condE numerator; B' = -2*ln2*D)
//   F = sum Phi(d)                 (cdf-sum, DIRECT via 3-term erf reusing g)
//   D = sum dp*ev*g
// ---------------------------------------------------------------------------
__global__ __launch_bounds__(RB) void gt_kernel(
    const float* __restrict__ xs, const float* __restrict__ evs,
    float* __restrict__ gbuf, int n) {
  float x0, hx;
  grid_geom(xs, n, &x0, &hx);
  int m = blockIdx.x * RB + threadIdx.x;        // gridDim.x = GM/RB
  float xm = fmaf((float)m, hx, x0);
  const int chunk = n / YS;
  int jb = blockIdx.y * chunk;
  const float P2S = 0.39169197f;   // 0.47047*sqrt(ln2): t = 1/(1+p|d|/sqrt2)
  float a = 0.0f, b = 0.0f, f = 0.0f, d = 0.0f;
  #pragma unroll 8
  for (int jj = 0; jj < chunk; ++jj) {
    float xj = xs[jb + jj];                      // uniform -> s_load
    float ev = evs[jb + jj];
    float dp = xm - xj;
    float g = __builtin_amdgcn_exp2f(-(dp * dp));  // exp(-d^2/2)
    float evg = ev * g;
    a += g;
    b += evg;
    d = fmaf(dp, evg, d);
    // A&S 7.1.25 erf (p=0.47047, |err|<=2.5e-5), reuses g
    float tt = __builtin_amdgcn_rcpf(fmaf(P2S, __builtin_fabsf(dp), 1.0f));
    float poly = tt * (0.3480242f + tt * (-0.0958798f + tt * 0.7478556f));
    f += __builtin_copysignf(fmaf(-poly, g, 1.0f), dp);   // sign*erf
  }
  atomicAdd(&gbuf[m], a);
  atomicAdd(&gbuf[GM + m], b);
  atomicAdd(&gbuf[2 * GM + m], 0.5f * (float)chunk + 0.5f * f);  // Phi = .5+.5*s
  atomicAdd(&gbuf[3 * GM + m], d);
}

// ---------------------------------------------------------------------------
// Per-element cubic Hermite interpolation of FPhi (cdf-sum) and B (pdf*ev
// sum), then the loss terms. One atomic per block.
// ---------------------------------------------------------------------------
__global__ __launch_bounds__(RB) void final_kernel(
    const float* __restrict__ xs, const float* __restrict__ evs,
    const float* __restrict__ th_s, const float* __restrict__ gbuf,
    float* __restrict__ out, int n) {
  float x0, hx;
  grid_geom(xs, n, &x0, &hx);
  const float* A = gbuf;
  const float* B = gbuf + GM;
  const float* F = gbuf + 2 * GM;
  const float* D = gbuf + 3 * GM;
  int i = blockIdx.x * RB + threadIdx.x;

  float term = 0.0f;
  if (i < n) {
    float x = xs[i];
    double u = ((double)x - (double)x0) / (double)hx;
    int m = (int)u;
    m = min(max(m, 0), GM - 2);
    float t = (float)(u - (double)m);
    float t2 = t * t, t3 = t2 * t;
    float h00 = 2.0f * t3 - 3.0f * t2 + 1.0f;
    float h01 = 3.0f * t2 - 2.0f * t3;
    float h10 = t3 - 2.0f * t2 + t;
    float h11 = t3 - t2;
    float Fi = F[m] * h00 + F[m + 1] * h01 +
               hx * KFP * (A[m] * h10 + A[m + 1] * h11);
    float Bi = B[m] * h00 + B[m + 1] * h01 -
               2.0f * LN2 * hx * (D[m] * h10 + D[m + 1] * h11);
    const float fn = (float)n;
    float condE = fmaxf(Bi, 0.0f) * (1.0f / SQRT2PI) / fn + fn * 1e-32f;
    float surv = fmaxf(Fi, 0.25f) / fn;    // exact math gives Fi >= 0.5
    term = (__logf(condE) - __logf(surv) + th_s[i]) * evs[i];
  }

  #pragma unroll
  for (int off = 32; off > 0; off >>= 1) term += __shfl_down(term, off, 64);
  __shared__ float red[RB / 64];
  int wave = threadIdx.x >> 6, lane = threadIdx.x & 63;
  if (lane == 0) red[wave] = term;
  __syncthreads();
  if (threadIdx.x == 0) {
    float s = 0.0f;
    #pragma unroll
    for (int w = 0; w < RB / 64; ++w) s += red[w];
    atomicAdd(out, -s / (float)n);
  }
}

extern "C" void kernel_launch(void* const* d_in, const int* in_sizes, int n_in,
                              void* d_out, int out_size, void* d_ws, size_t ws_size,
                              hipStream_t stream) {
  const float* theta = (const float*)d_in[0];   // log_h (n,1) fp32
  const float* dur   = (const float*)d_in[1];   // durations (n,) fp32
  const int*   ev    = (const int*)d_in[2];     // events (n,) int32
  float* out = (float*)d_out;
  const int n = in_sizes[1];

  // workspace layout (8-byte aligned first)
  char* ws = (char*)d_ws;
  uint64_t* key  = (uint64_t*)ws;  ws += n * sizeof(uint64_t);
  float*    xs   = (float*)ws;     ws += n * sizeof(float);
  float*    evs  = (float*)ws;     ws += n * sizeof(float);
  float*    e    = (float*)ws;     ws += n * sizeof(float);
  int*      rank = (int*)ws;       ws += n * sizeof(int);
  float*    th_s = (float*)ws;     ws += n * sizeof(float);
  float*    gbuf = (float*)ws;     ws += 4 * GM * sizeof(float);  // A|B|F|D

  int nb = (n + RB - 1) / RB;                    // 32; covers 4*GM too (n==8192)
  int nbp = (max(n, 4 * GM) + RB - 1) / RB;
  prep_kernel<<<nbp, RB, 0, stream>>>(theta, dur, e, key, rank, out, gbuf, n);
  rank_kernel<<<dim3(n / RB, n / JT), RB, 0, stream>>>(key, rank, n);
  scatter_kernel<<<nb, RB, 0, stream>>>(e, rank, ev, theta, xs, evs, th_s, n);
  gt_kernel<<<dim3(GM / RB, YS), RB, 0, stream>>>(xs, evs, gbuf, n);
  final_kernel<<<nb, RB, 0, stream>>>(xs, evs, th_s, gbuf, out, n);
}